// Round 5
// baseline (622.563 us; speedup 1.0000x reference)
//
#include <hip/hip_runtime.h>
#include <math.h>

#define TOKENS 16384
#define DMODEL 2048
#define NEXP   256
#define TOPK   8
#define BM     16
#define BK     16
#define NCHUNK (DMODEL / BK)       // 128
#define GRID_MAIN (TOKENS / BM)    // 1024

#define OFF_IDX  ((size_t)TOKENS * TOPK)
#define OFF_CNT  ((size_t)2 * TOKENS * TOPK)
#define OFF_SCAL (OFF_CNT + NEXP)

// ---- stats: std(ddof=1)/mean, max, min, expected ; sm = 256-float scratch ----
__device__ __forceinline__ void stats_from_counts(float* __restrict__ out,
                                                  float* __restrict__ sm,
                                                  int t, float c) {
    sm[t] = c; __syncthreads();
    for (int s = 128; s > 0; s >>= 1) { if (t < s) sm[t] += sm[t + s]; __syncthreads(); }
    float mean = sm[0] * (1.0f / NEXP);
    __syncthreads();
    float d = c - mean;
    sm[t] = d * d; __syncthreads();
    for (int s = 128; s > 0; s >>= 1) { if (t < s) sm[t] += sm[t + s]; __syncthreads(); }
    float var = sm[0] * (1.0f / (NEXP - 1));
    __syncthreads();
    sm[t] = c; __syncthreads();
    for (int s = 128; s > 0; s >>= 1) { if (t < s) sm[t] = fmaxf(sm[t], sm[t + s]); __syncthreads(); }
    float mx = sm[0]; __syncthreads();
    sm[t] = c; __syncthreads();
    for (int s = 128; s > 0; s >>= 1) { if (t < s) sm[t] = fminf(sm[t], sm[t + s]); __syncthreads(); }
    float mn = sm[0];
    if (t == 0) {
        out[OFF_SCAL + 0] = sqrtf(var) / (mean + 1e-6f);
        out[OFF_SCAL + 1] = mx;
        out[OFF_SCAL + 2] = mn;
        out[OFF_SCAL + 3] = (float)(TOKENS * TOPK) / (float)NEXP;  // 512
    }
}

// ---- transpose w (E x D) -> wT (D x E); block 0 zeroes counts+counter ----
__global__ __launch_bounds__(256) void k_prep(const float* __restrict__ w,
                                              float* __restrict__ wT,
                                              float* __restrict__ out,
                                              int* __restrict__ counter) {
    __shared__ float tile[32][33];
    const int bx = blockIdx.x & 63;        // d-tile (64 tiles)
    const int by = blockIdx.x >> 6;        // e-tile (8 tiles)
    const int lx = threadIdx.x & 31;
    const int lyb = threadIdx.x >> 5;      // 0..7
#pragma unroll
    for (int r = 0; r < 4; r++) {
        int ly = lyb + 8 * r;
        tile[ly][lx] = w[(size_t)(by * 32 + ly) * DMODEL + bx * 32 + lx];
    }
    __syncthreads();
#pragma unroll
    for (int r = 0; r < 4; r++) {
        int ly = lyb + 8 * r;
        wT[(size_t)(bx * 32 + ly) * NEXP + by * 32 + lx] = tile[lx][ly];
    }
    if (blockIdx.x == 0) {
        out[OFF_CNT + threadIdx.x] = 0.0f;
        if (counter && threadIdx.x == 0) *counter = 0;
    }
}

// ---- stage one 16x256 w-chunk (16 KB) into LDS buffer `dst` ----
__device__ __forceinline__ void stage_chunk(const float4* __restrict__ wT4,
                                            float* __restrict__ dst,
                                            int chunk, int tid) {
#if defined(__HIP_DEVICE_COMPILE__) && __has_builtin(__builtin_amdgcn_global_load_lds)
    // async DMA: lds dest = wave-uniform base + lane*16 (no per-lane scatter)
    const float4* g = wT4 + chunk * (BK * NEXP / 4) + tid;
    float* lb = dst + (size_t)(tid & 192) * 4;        // wave-uniform float offset
#pragma unroll
    for (int r = 0; r < 4; r++)
        __builtin_amdgcn_global_load_lds(
            (const __attribute__((address_space(1))) void*)(g + r * 256),
            (__attribute__((address_space(3))) void*)(lb + r * 1024),
            16, 0, 0);
#else
#pragma unroll
    for (int r = 0; r < 4; r++) {
        float4 v = wT4[chunk * (BK * NEXP / 4) + tid + r * 256];
        *(float4*)(dst + (size_t)(tid + r * 256) * 4) = v;
    }
#endif
}

// ---- main: GEMM (wave-uniform tokens, sequential-K) + top-8 + softmax + hist ----
__global__ __launch_bounds__(256, 4) void k_main(
        const float* __restrict__ x,
        const float* __restrict__ wT,      // (D x E)
        const float* __restrict__ bias,
        float* __restrict__ out,
        int* __restrict__ counter) {
    __shared__ float wSf[2][BK][NEXP];     // 32 KB double-buffered w chunks
    __shared__ float hist[NEXP];           // 1 KB
    __shared__ int   isLast;

    const int tid  = threadIdx.x;
    const int lane = tid & 63;
    const int wv   = tid >> 6;             // 0..3; wave owns tokens wv*4..+3
    const int tok0 = blockIdx.x * BM + wv * 4;

    hist[tid] = 0.0f;

    float acc[4][4];                       // 4 tokens x 4 experts (lane*4..+3)
#pragma unroll
    for (int t = 0; t < 4; t++)
#pragma unroll
        for (int e = 0; e < 4; e++) acc[t][e] = 0.0f;

    const float4* wT4 = (const float4*)wT;
    const float*  xb  = x + (size_t)tok0 * DMODEL;

    stage_chunk(wT4, &wSf[0][0][0], 0, tid);
    __syncthreads();                       // drains vmcnt -> buf0 ready

    for (int i = 0; i < NCHUNK; i++) {
        const int b = i & 1;
        if (i + 1 < NCHUNK) stage_chunk(wT4, &wSf[b ^ 1][0][0], i + 1, tid);

        const float* xc = xb + i * BK;
        // prefetch the whole chunk's x (wave-uniform addresses: L1 broadcast)
        float4 av[4][4];                   // [ks][token], constant indices only
#pragma unroll
        for (int ks = 0; ks < 4; ks++)
#pragma unroll
            for (int t = 0; t < 4; t++)
                av[ks][t] = *(const float4*)(xc + (size_t)t * DMODEL + ks * 4);

#pragma unroll
        for (int ks = 0; ks < 4; ks++) {
#pragma unroll
            for (int kk = 0; kk < 4; kk++) {
                float4 bv = *(const float4*)&wSf[b][ks * 4 + kk][lane * 4];
#pragma unroll
                for (int t = 0; t < 4; t++) {
                    float a = (kk == 0) ? av[ks][t].x : (kk == 1) ? av[ks][t].y
                            : (kk == 2) ? av[ks][t].z : av[ks][t].w;
                    acc[t][0] = fmaf(a, bv.x, acc[t][0]);
                    acc[t][1] = fmaf(a, bv.y, acc[t][1]);
                    acc[t][2] = fmaf(a, bv.z, acc[t][2]);
                    acc[t][3] = fmaf(a, bv.w, acc[t][3]);
                }
            }
        }
        __syncthreads();                   // drains next chunk's DMA; frees buf b
    }

    // ---- top-8 per token, straight from registers (r1-verified semantics) ----
    float4 bb = *(const float4*)&bias[lane * 4];
#pragma unroll
    for (int tt = 0; tt < 4; tt++) {
        float lv[4] = {acc[tt][0] + bb.x, acc[tt][1] + bb.y,
                       acc[tt][2] + bb.z, acc[tt][3] + bb.w};
        int msk = 0xF;
        float topv[TOPK];
        int   topi[TOPK];
#pragma unroll
        for (int r = 0; r < TOPK; r++) {
            float bvv = -INFINITY;
            int   bii = 0x7fffffff;
#pragma unroll
            for (int j = 0; j < 4; j++) {
                if (msk & (1 << j)) {
                    float vv = lv[j];
                    int   ii = lane * 4 + j;
                    if (vv > bvv || (vv == bvv && ii < bii)) { bvv = vv; bii = ii; }
                }
            }
#pragma unroll
            for (int off = 32; off > 0; off >>= 1) {
                float ov = __shfl_xor(bvv, off);
                int   oi = __shfl_xor(bii, off);
                if (ov > bvv || (ov == bvv && oi < bii)) { bvv = ov; bii = oi; }
            }
            topv[r] = bvv;
            topi[r] = bii;
            if ((bii >> 2) == lane) msk &= ~(1 << (bii & 3));
        }
        float m = topv[0];
        float s = 0.0f;
#pragma unroll
        for (int r = 0; r < TOPK; r++) s += expf(topv[r] - m);

        const int gtok = tok0 + tt;
        if (lane < TOPK) {
            out[(size_t)gtok * TOPK + lane] = expf(topv[lane] - m) / s;
        } else if (lane < 2 * TOPK) {
            int r = lane - TOPK;
            out[OFF_IDX + (size_t)gtok * TOPK + r] = (float)topi[r];
            atomicAdd(&hist[topi[r]], 1.0f);
        }
    }
    __syncthreads();
    float hv = hist[tid];
    if (hv != 0.0f) atomicAdd(&out[OFF_CNT + tid], hv);

    // ---- last block computes the stats (r2-verified device-scope protocol) ----
    if (counter) {
        __syncthreads();
        if (tid == 0) {
            __threadfence();
            int old = atomicAdd(counter, 1);
            isLast = (old == GRID_MAIN - 1) ? 1 : 0;
        }
        __syncthreads();
        if (isLast) {
            __threadfence();
            float c = __hip_atomic_load(&out[OFF_CNT + tid], __ATOMIC_RELAXED,
                                        __HIP_MEMORY_SCOPE_AGENT);
            stats_from_counts(out, &wSf[0][0][0], tid, c);
        }
    }
}

// ---- fallback stats kernel (only if workspace lacks room for the counter) ----
__global__ __launch_bounds__(256) void k_stats(float* __restrict__ out) {
    __shared__ float sm[NEXP];
    stats_from_counts(out, sm, threadIdx.x, out[OFF_CNT + threadIdx.x]);
}

extern "C" void kernel_launch(void* const* d_in, const int* in_sizes, int n_in,
                              void* d_out, int out_size, void* d_ws, size_t ws_size,
                              hipStream_t stream) {
    const float* x    = (const float*)d_in[0];
    const float* w    = (const float*)d_in[1];
    const float* bias = (const float*)d_in[2];
    float* out = (float*)d_out;

    const size_t wT_bytes = (size_t)DMODEL * NEXP * sizeof(float);
    float* wT = (float*)d_ws;
    const bool fused = (ws_size >= wT_bytes + 256);
    int* counter = fused ? (int*)((char*)d_ws + wT_bytes) : nullptr;

    k_prep<<<512, 256, 0, stream>>>(w, wT, out, counter);
    k_main<<<GRID_MAIN, 256, 0, stream>>>(x, wT, bias, out, counter);
    if (!fused) k_stats<<<1, 256, 0, stream>>>(out);
}